// Round 1
// 1846.480 us; speedup vs baseline: 1.0927x; 1.0927x over previous
//
#include <hip/hip_runtime.h>
#include <math.h>

// ============================================================
// K1: ps[n][j] = sum_f xt[n][t][f] * W_pre[t][32+f][g]   (src-part, gathered later)
// ============================================================
__global__ __launch_bounds__(256) void pre_kernel(
    const float* __restrict__ x, const float* __restrict__ W_pre,
    float* __restrict__ ps)
{
  __shared__ float xl[2][128];
  const int tid = threadIdx.x;
  const int nl  = tid >> 7;
  const int j   = tid & 127;
  const int n   = blockIdx.x * 2 + nl;
  xl[nl][j] = x[(size_t)n * 128 + j];
  __syncthreads();
  const int t = j >> 5, g = j & 31;
  const float* xp = &xl[nl][t * 32];
  const float* Ws = W_pre + (size_t)(t * 96 + 32) * 32 + g;   // rows 32..63
  float aps = 0.f;
#pragma unroll
  for (int f = 0; f < 32; ++f) aps += xp[f] * Ws[f * 32];
  ps[(size_t)n * 128 + j] = aps;
}

// ============================================================
// K2: degree count
// ============================================================
__global__ __launch_bounds__(256) void count_kernel(
    const int* __restrict__ ei, int* __restrict__ cnt, int E)
{
  const int e = blockIdx.x * 256 + threadIdx.x;
  if (e < E) atomicAdd(&cnt[ei[E + e]], 1);
}

// ============================================================
// K3: exclusive scan of cnt (N = 65536 = 256 threads x 256 elems), one block
// ============================================================
__global__ __launch_bounds__(256) void scan_kernel(
    const int* __restrict__ cnt, int* __restrict__ base, int* __restrict__ fill)
{
  __shared__ int part[256];
  const int tid = threadIdx.x;
  const int c0 = tid * 256;
  int s = 0;
  for (int i = 0; i < 256; ++i) s += cnt[c0 + i];
  part[tid] = s;
  __syncthreads();
  if (tid == 0) {
    int run = 0;
    for (int i = 0; i < 256; ++i) { int t = part[i]; part[i] = run; run += t; }
  }
  __syncthreads();
  int run = part[tid];
  for (int i = 0; i < 256; ++i) {
    int cc = cnt[c0 + i];
    base[c0 + i] = run;
    fill[c0 + i] = run;
    run += cc;
  }
}

// ============================================================
// K4 (new): fused scatter + edge-transform.
// For each edge (streaming order): slot = atomicAdd(fill[dst]),
// srcs_s[slot] = src, e_sorted[slot][0..31] = W_edge @ ea + b_edge.
// edge_attr is read STREAMING (coalesced, exactly once); e_sorted rows are
// 128-B aligned full-line scattered writes. One wave handles 4 edges.
// ============================================================
__global__ __launch_bounds__(256) void escatter_kernel(
    const float* __restrict__ edge_attr, const int* __restrict__ ei,
    const float* __restrict__ W_edge, const float* __restrict__ b_edge,
    int* __restrict__ fill, int* __restrict__ srcs_s,
    float* __restrict__ e_sorted, int E)
{
  __shared__ float sEA[4][2][128];    // per-wave double buffer
  const int tid  = threadIdx.x;
  const int lane = tid & 63;
  const int w    = tid >> 6;
  const int g    = lane & 31;
  const int half = lane >> 5;
  const int e4   = (blockIdx.x * 4 + w) * 4;
  if (e4 >= E) return;
  const int nv = min(4, E - e4);

  // W_edge rows in registers: we[k] = W_edge[g][half*64 + k]
  float we[64];
  {
    const float4* wrow = (const float4*)(W_edge + (size_t)g * 128 + half * 64);
#pragma unroll
    for (int k = 0; k < 16; ++k) {
      const float4 q = wrow[k];
      we[4*k] = q.x; we[4*k+1] = q.y; we[4*k+2] = q.z; we[4*k+3] = q.w;
    }
  }
  const float bedge = b_edge[g];

  // slots for up to 4 edges (lanes 0..3 do the atomics)
  int slot = 0;
  if (lane < nv) {
    const int e = e4 + lane;
    const int d = ei[E + e];
    const int s = ei[e];
    slot = atomicAdd(&fill[d], 1);
    srcs_s[slot] = s;
  }

  // prefetch all 4 rows (sequential 2 KB per wave)
  float2 va[4];
#pragma unroll
  for (int l = 0; l < 4; ++l) {
    const int el = (l < nv) ? (e4 + l) : e4;
    va[l] = *(const float2*)(edge_attr + (size_t)el * 128 + lane * 2);
  }

#pragma unroll
  for (int l = 0; l < 4; ++l) {
    if (l >= nv) break;
    *(float2*)&sEA[w][l & 1][lane * 2] = va[l];
    float acc = 0.f;
    const float4* eap = (const float4*)&sEA[w][l & 1][half * 64];
#pragma unroll
    for (int k = 0; k < 16; ++k) {
      const float4 q = eap[k];
      acc += q.x * we[4*k] + q.y * we[4*k+1] + q.z * we[4*k+2] + q.w * we[4*k+3];
    }
    acc += __shfl_xor(acc, 32);
    const int sl = __shfl(slot, l);
    if (half == 0) e_sorted[(size_t)sl * 32 + g] = acc + bedge;
  }
}

// ============================================================
// K5: one wave per node. e is PRECOMPUTED (e_sorted, CSR order, streaming).
// m = etrans(e) + pd + ps[src]; aggregate in registers.
// Edges processed in PAIRS: half-wave loads e-row of edge i, other half of
// edge i+1 (one coalesced 256-B load); next pair's e + ps prefetched into
// registers one iteration ahead. No atomics, no __syncthreads.
// ============================================================
__global__ __launch_bounds__(256) void agg_kernel(
    const float* __restrict__ x,
    const float* __restrict__ W_pre, const float* __restrict__ b_pre,
    const float* __restrict__ ps, const float* __restrict__ e_sorted,
    const int* __restrict__ srcs_s, const int* __restrict__ cnt,
    const int* __restrict__ base, float* __restrict__ aggs)
{
  __shared__ float sE[4][2][64];  // [wave][buf][pair of e-rows]
  __shared__ float sX[4][128];    // x row, per wave
  const int tid  = threadIdx.x;
  const int lane = tid & 63;
  const int w    = tid >> 6;
  const int g    = lane & 31;
  const int half = lane >> 5;
  const int t0   = half;          // tower of j0 = lane; j1 = lane+64 -> tower t0+2
  const int n    = blockIdx.x * 4 + w;

  // ---- W_pre e-part weights in registers ----
  float wp0[32], wp1[32];         // rows 64..95, columns for j0 / j1
#pragma unroll
  for (int f = 0; f < 32; ++f) {
    wp0[f] = W_pre[(size_t)(t0 * 96 + 64 + f) * 32 + g];
    wp1[f] = W_pre[(size_t)((t0 + 2) * 96 + 64 + f) * 32 + g];
  }

  // ---- stage x row, compute pd (dst-part, once per node) ----
  sX[w][lane]      = x[(size_t)n * 128 + lane];
  sX[w][lane + 64] = x[(size_t)n * 128 + 64 + lane];
  float pd0 = b_pre[t0 * 32 + g];
  float pd1 = b_pre[(t0 + 2) * 32 + g];
#pragma unroll
  for (int f = 0; f < 32; ++f) {
    pd0 += sX[w][t0 * 32 + f]       * W_pre[(size_t)(t0 * 96 + f) * 32 + g];
    pd1 += sX[w][(t0 + 2) * 32 + f] * W_pre[(size_t)((t0 + 2) * 96 + f) * 32 + g];
  }

  // ---- edge loop (pairs, depth-1 prefetch) ----
  const int c  = cnt[n];
  const int b0 = base[n];
  float sum0 = 0.f, sum1 = 0.f, sq0 = 0.f, sq1 = 0.f;
  float mx0 = -INFINITY, mx1 = -INFINITY, mn0 = INFINITY, mn1 = INFINITY;

  float ev = 0.f, pA0 = 0.f, pA1 = 0.f, pB0 = 0.f, pB1 = 0.f;
  if (c > 0) {
    const int cm = c - 1;
    ev = e_sorted[(size_t)(b0 + min(half, cm)) * 32 + g];
    const int sA = srcs_s[b0];
    const int sB = srcs_s[b0 + min(1, cm)];
    pA0 = ps[(size_t)sA * 128 + lane];
    pA1 = ps[(size_t)sA * 128 + 64 + lane];
    pB0 = ps[(size_t)sB * 128 + lane];
    pB1 = ps[(size_t)sB * 128 + 64 + lane];
  }

  for (int i = 0; i < c; i += 2) {
    const int buf = (i >> 1) & 1;
    const int cm  = c - 1;
    // prefetch pair i+2 (clamped; harmless cached re-reads at the tail)
    const float ev_n = e_sorted[(size_t)(b0 + min(i + 2 + half, cm)) * 32 + g];
    const int sAn = srcs_s[b0 + min(i + 2, cm)];
    const int sBn = srcs_s[b0 + min(i + 3, cm)];
    const float pA0n = ps[(size_t)sAn * 128 + lane];
    const float pA1n = ps[(size_t)sAn * 128 + 64 + lane];
    const float pB0n = ps[(size_t)sBn * 128 + lane];
    const float pB1n = ps[(size_t)sBn * 128 + 64 + lane];

    // stage current pair's e rows (lanes 0-31: edge i, lanes 32-63: edge i+1)
    sE[w][buf][lane] = ev;

    // edge i
    {
      float a0 = 0.f, a1 = 0.f;
      const float4* ep = (const float4*)&sE[w][buf][0];
#pragma unroll
      for (int k = 0; k < 8; ++k) {
        const float4 q = ep[k];
        a0 += q.x * wp0[4*k] + q.y * wp0[4*k+1] + q.z * wp0[4*k+2] + q.w * wp0[4*k+3];
        a1 += q.x * wp1[4*k] + q.y * wp1[4*k+1] + q.z * wp1[4*k+2] + q.w * wp1[4*k+3];
      }
      const float m0 = a0 + pd0 + pA0;
      const float m1 = a1 + pd1 + pA1;
      sum0 += m0; sq0 += m0 * m0; mx0 = fmaxf(mx0, m0); mn0 = fminf(mn0, m0);
      sum1 += m1; sq1 += m1 * m1; mx1 = fmaxf(mx1, m1); mn1 = fminf(mn1, m1);
    }
    // edge i+1 (wave-uniform branch)
    if (i + 1 < c) {
      float a0 = 0.f, a1 = 0.f;
      const float4* ep = (const float4*)&sE[w][buf][32];
#pragma unroll
      for (int k = 0; k < 8; ++k) {
        const float4 q = ep[k];
        a0 += q.x * wp0[4*k] + q.y * wp0[4*k+1] + q.z * wp0[4*k+2] + q.w * wp0[4*k+3];
        a1 += q.x * wp1[4*k] + q.y * wp1[4*k+1] + q.z * wp1[4*k+2] + q.w * wp1[4*k+3];
      }
      const float m0 = a0 + pd0 + pB0;
      const float m1 = a1 + pd1 + pB1;
      sum0 += m0; sq0 += m0 * m0; mx0 = fmaxf(mx0, m0); mn0 = fminf(mn0, m0);
      sum1 += m1; sq1 += m1 * m1; mx1 = fmaxf(mx1, m1); mn1 = fminf(mn1, m1);
    }
    // rotate prefetch registers
    ev = ev_n; pA0 = pA0n; pA1 = pA1n; pB0 = pB0n; pB1 = pB1n;
  }

  // ---- finalize ----
  const float csafe = fmaxf((float)c, 1.f);
  const float mean0 = sum0 / csafe, mean1 = sum1 / csafe;
  const float sd0 = sqrtf(fmaxf(sq0 / csafe - mean0 * mean0, 0.f) + 1e-5f);
  const float sd1 = sqrtf(fmaxf(sq1 / csafe - mean1 * mean1, 0.f) + 1e-5f);
  if (c == 0) { mx0 = mx1 = mn0 = mn1 = 0.f; }
  float* ag = aggs + (size_t)n * 512;
  ag[lane]       = mean0; ag[64 + lane]  = mean1;
  ag[128 + lane] = mx0;   ag[192 + lane] = mx1;
  ag[256 + lane] = mn0;   ag[320 + lane] = mn1;
  ag[384 + lane] = sd0;   ag[448 + lane] = sd1;
}

// ============================================================
// K6: scalers + W_post + W_lin + residual (8 nodes/block, 4-acc W reuse)
// ============================================================
__global__ __launch_bounds__(256) void post_kernel(
    const float* __restrict__ x, const float* __restrict__ aggs,
    const int* __restrict__ cnt,
    const float* __restrict__ W_post, const float* __restrict__ b_post,
    const float* __restrict__ W_lin, const float* __restrict__ b_lin,
    float* __restrict__ out, float avg_log)
{
  __shared__ float vec[8][4][416];
  __shared__ float h2[8][128];
  const int tid = threadIdx.x;
  const int j = tid & 127;
  const int t = j >> 5, g = j & 31;
  const int n0 = blockIdx.x * 8;

  // phase 1: build 416-feature per-tower vectors for 8 nodes
  for (int itn = 0; itn < 4; ++itn) {
    const int nl = itn * 2 + (tid >> 7);
    const int n = n0 + nl;
    const size_t o = (size_t)n * 128 + j;
    const float* ag = aggs + (size_t)n * 512;
    const float c = (float)cnt[n];
    const float mean = ag[j];
    const float mx   = ag[128 + j];
    const float mn   = ag[256 + j];
    const float sd   = ag[384 + j];
    const float logd = logf(c + 1.f);
    const float amp_s = logd / avg_log;
    const float att_s = (c == 0.f) ? 1.f : (avg_log / logd);
    float* v = vec[nl][t];
    v[g]        = x[o];
    v[32 + g]   = mean;          v[64 + g]   = mx;
    v[96 + g]   = mn;            v[128 + g]  = sd;
    v[160 + g]  = mean * amp_s;  v[192 + g]  = mx * amp_s;
    v[224 + g]  = mn * amp_s;    v[256 + g]  = sd * amp_s;
    v[288 + g]  = mean * att_s;  v[320 + g]  = mx * att_s;
    v[352 + g]  = mn * att_s;    v[384 + g]  = sd * att_s;
  }
  __syncthreads();

  // phase 2: h2 = vec @ W_post + b_post (4 node-accs per thread)
  {
    const int nlb = tid >> 7;
    const float b = b_post[t * 32 + g];
    float acc0 = b, acc1 = b, acc2 = b, acc3 = b;
    const float* Wp = W_post + (size_t)(t * 416) * 32 + g;
    const float* v0 = vec[nlb + 0][t];
    const float* v1 = vec[nlb + 2][t];
    const float* v2 = vec[nlb + 4][t];
    const float* v3 = vec[nlb + 6][t];
    for (int f = 0; f < 416; ++f) {
      const float wv = Wp[(size_t)f * 32];
      acc0 += v0[f] * wv; acc1 += v1[f] * wv;
      acc2 += v2[f] * wv; acc3 += v3[f] * wv;
    }
    h2[nlb + 0][j] = acc0; h2[nlb + 2][j] = acc1;
    h2[nlb + 4][j] = acc2; h2[nlb + 6][j] = acc3;
  }
  __syncthreads();

  // phase 3: out = h2 @ W_lin.T + b_lin + x
  {
    const int nlb = tid >> 7;
    const float* Wl = W_lin + (size_t)j * 128;
    const float bl = b_lin[j];
    float a0 = bl, a1 = bl, a2 = bl, a3 = bl;
    const float* h0 = h2[nlb + 0];
    const float* h1 = h2[nlb + 2];
    const float* hp = h2[nlb + 4];
    const float* h3 = h2[nlb + 6];
    for (int k = 0; k < 128; ++k) {
      const float wv = Wl[k];
      a0 += h0[k] * wv; a1 += h1[k] * wv;
      a2 += hp[k] * wv; a3 += h3[k] * wv;
    }
    const size_t b0 = (size_t)(n0 + nlb + 0) * 128 + j;
    const size_t b1 = (size_t)(n0 + nlb + 2) * 128 + j;
    const size_t b2 = (size_t)(n0 + nlb + 4) * 128 + j;
    const size_t b3 = (size_t)(n0 + nlb + 6) * 128 + j;
    out[b0] = a0 + x[b0];
    out[b1] = a1 + x[b1];
    out[b2] = a2 + x[b2];
    out[b3] = a3 + x[b3];
  }
}

extern "C" void kernel_launch(void* const* d_in, const int* in_sizes, int n_in,
                              void* d_out, int out_size, void* d_ws, size_t ws_size,
                              hipStream_t stream) {
  const float* x         = (const float*)d_in[0];
  const float* edge_attr = (const float*)d_in[1];
  const int*   ei        = (const int*)  d_in[2];
  const float* W_edge    = (const float*)d_in[3];
  const float* b_edge    = (const float*)d_in[4];
  const float* W_pre     = (const float*)d_in[5];
  const float* b_pre     = (const float*)d_in[6];
  const float* W_post    = (const float*)d_in[7];
  const float* b_post    = (const float*)d_in[8];
  const float* W_lin     = (const float*)d_in[9];
  const float* b_lin     = (const float*)d_in[10];
  float* out = (float*)d_out;

  const int N = in_sizes[0] / 128;
  const int E = in_sizes[2] / 2;

  // workspace: ps (N*128 f), aggs (N*512 f), e_sorted (E*32 f),
  //            srcs_s (E), cnt/base/fill (N each)
  float* ps       = (float*)d_ws;
  float* aggs     = ps + (size_t)N * 128;
  float* e_sorted = aggs + (size_t)N * 512;
  int*   srcs_s   = (int*)(e_sorted + (size_t)E * 32);
  int*   cnt      = srcs_s + E;
  int*   base     = cnt + N;
  int*   fill     = base + N;

  hipMemsetAsync(cnt, 0, (size_t)N * 4, stream);

  const double counts[6] = {108477.0, 299931.0, 180702.0, 10767.0, 3.0, 2.0};
  double num = 0.0, den = 0.0;
  for (int i = 0; i < 6; ++i) { num += counts[i] * log((double)(i + 2)); den += counts[i]; }
  const float avg_log = (float)(num / den);

  pre_kernel<<<N / 2, 256, 0, stream>>>(x, W_pre, ps);
  count_kernel<<<(E + 255) / 256, 256, 0, stream>>>(ei, cnt, E);
  scan_kernel<<<1, 256, 0, stream>>>(cnt, base, fill);
  escatter_kernel<<<(E + 15) / 16, 256, 0, stream>>>(edge_attr, ei, W_edge, b_edge,
                                                     fill, srcs_s, e_sorted, E);
  agg_kernel<<<N / 4, 256, 0, stream>>>(x, W_pre, b_pre, ps, e_sorted,
                                        srcs_s, cnt, base, aggs);
  post_kernel<<<N / 8, 256, 0, stream>>>(x, aggs, cnt, W_post, b_post,
                                         W_lin, b_lin, out, avg_log);
}

// Round 2
// 1777.338 us; speedup vs baseline: 1.1353x; 1.0389x over previous
//
#include <hip/hip_runtime.h>
#include <math.h>

// ============================================================
// K1: ps[n][j] = sum_f xt[n][t][f] * W_pre[t][32+f][g]   (src-part, gathered later)
// ============================================================
__global__ __launch_bounds__(256) void pre_kernel(
    const float* __restrict__ x, const float* __restrict__ W_pre,
    float* __restrict__ ps)
{
  __shared__ float xl[2][128];
  const int tid = threadIdx.x;
  const int nl  = tid >> 7;
  const int j   = tid & 127;
  const int n   = blockIdx.x * 2 + nl;
  xl[nl][j] = x[(size_t)n * 128 + j];
  __syncthreads();
  const int t = j >> 5, g = j & 31;
  const float* xp = &xl[nl][t * 32];
  const float* Ws = W_pre + (size_t)(t * 96 + 32) * 32 + g;   // rows 32..63
  float aps = 0.f;
#pragma unroll
  for (int f = 0; f < 32; ++f) aps += xp[f] * Ws[f * 32];
  ps[(size_t)n * 128 + j] = aps;
}

// ============================================================
// K2: degree count
// ============================================================
__global__ __launch_bounds__(256) void count_kernel(
    const int* __restrict__ ei, int* __restrict__ cnt, int E)
{
  const int e = blockIdx.x * 256 + threadIdx.x;
  if (e < E) atomicAdd(&cnt[ei[E + e]], 1);
}

// ============================================================
// K3: exclusive scan of cnt (N = 65536 = 256 threads x 256 elems), one block
// ============================================================
__global__ __launch_bounds__(256) void scan_kernel(
    const int* __restrict__ cnt, int* __restrict__ base, int* __restrict__ fill)
{
  __shared__ int part[256];
  const int tid = threadIdx.x;
  const int c0 = tid * 256;
  int s = 0;
  const int4* c4 = (const int4*)(cnt + c0);
  for (int i = 0; i < 64; ++i) { const int4 v = c4[i]; s += v.x + v.y + v.z + v.w; }
  part[tid] = s;
  __syncthreads();
  if (tid == 0) {
    int run = 0;
    for (int i = 0; i < 256; ++i) { int t = part[i]; part[i] = run; run += t; }
  }
  __syncthreads();
  int run = part[tid];
  for (int i = 0; i < 256; ++i) {
    int cc = cnt[c0 + i];
    base[c0 + i] = run;
    fill[c0 + i] = run;
    run += cc;
  }
}

// ============================================================
// K3b: transpose W_post[t][416][32] -> WpT[t][32][416] (one-time, tiny)
// ============================================================
__global__ __launch_bounds__(256) void wpt_kernel(
    const float* __restrict__ W_post, float* __restrict__ WpT)
{
  const int i = blockIdx.x * 256 + threadIdx.x;
  if (i >= 4 * 416 * 32) return;
  const int g = i & 31;
  const int f = (i >> 5) % 416;
  const int t = i / (416 * 32);
  WpT[((size_t)t * 32 + g) * 416 + f] = W_post[((size_t)t * 416 + f) * 32 + g];
}

// ============================================================
// K4: fused scatter + edge-transform, batched 16 edges/wave.
// 16 contiguous edge rows (8 KB) are DMA'd global->LDS with
// global_load_lds (16B/lane, no VGPR staging), then a mini-GEMM with 16
// INDEPENDENT accumulator chains (k outer, r inner) computes
// e = W_edge @ ea + b_edge for all 16 edges. Slots via atomicAdd as before.
// Wave-private LDS: no barriers.
// ============================================================
__global__ __launch_bounds__(256) void escatter_kernel(
    const float* __restrict__ edge_attr, const int* __restrict__ ei,
    const float* __restrict__ W_edge, const float* __restrict__ b_edge,
    int* __restrict__ fill, int* __restrict__ srcs_s,
    float* __restrict__ e_sorted, int E)
{
  __shared__ float sEA[4][16][128];     // 8 KB per wave
  const int tid  = threadIdx.x;
  const int lane = tid & 63;
  const int w    = tid >> 6;
  const int g    = lane & 31;
  const int half = lane >> 5;
  const int e0   = (blockIdx.x * 4 + w) * 16;
  if (e0 >= E) return;
  const int nv = min(16, E - e0);

  // W_edge rows in registers: we[k] = W_edge[g][half*64 + k]
  float we[64];
  {
    const float4* wrow = (const float4*)(W_edge + (size_t)g * 128 + half * 64);
#pragma unroll
    for (int k = 0; k < 16; ++k) {
      const float4 q = wrow[k];
      we[4*k] = q.x; we[4*k+1] = q.y; we[4*k+2] = q.z; we[4*k+3] = q.w;
    }
  }
  const float bedge = b_edge[g];

  // slots for up to 16 edges (lanes 0..15 do the atomics)
  int slot = 0;
  if (lane < nv) {
    const int e = e0 + lane;
    const int d = ei[E + e];
    const int s = ei[e];
    slot = atomicAdd(&fill[d], 1);
    srcs_s[slot] = s;
  }

  // ---- stage 16 rows (8 KB, contiguous) ----
  if (nv == 16) {
    const char* gbase = (const char*)(edge_attr + (size_t)e0 * 128) + (size_t)lane * 16;
    char* lbase = (char*)&sEA[w][0][0];
#pragma unroll
    for (int inst = 0; inst < 8; ++inst) {
      __builtin_amdgcn_global_load_lds(
          (const __attribute__((address_space(1))) void*)(gbase + inst * 1024),
          (__attribute__((address_space(3))) void*)(lbase + inst * 1024),
          16, 0, 0);
    }
    asm volatile("s_waitcnt vmcnt(0)" ::: "memory");
  } else {
    for (int r = 0; r < nv; ++r)
      *(float2*)&sEA[w][r][lane * 2] =
          *(const float2*)(edge_attr + (size_t)(e0 + r) * 128 + lane * 2);
  }

  // ---- 16 independent dot chains (broadcast LDS reads, 2-way alias = free) ----
  float acc[16];
#pragma unroll
  for (int r = 0; r < 16; ++r) acc[r] = 0.f;

  if (nv == 16) {
#pragma unroll
    for (int k = 0; k < 16; ++k) {
      const float w0 = we[4*k], w1 = we[4*k+1], w2 = we[4*k+2], w3 = we[4*k+3];
#pragma unroll
      for (int r = 0; r < 16; ++r) {
        const float4 q = *(const float4*)&sEA[w][r][half * 64 + k * 4];
        acc[r] += q.x * w0 + q.y * w1 + q.z * w2 + q.w * w3;
      }
    }
  } else {
    for (int r = 0; r < nv; ++r) {
      float a = 0.f;
#pragma unroll
      for (int k = 0; k < 16; ++k) {
        const float4 q = *(const float4*)&sEA[w][r][half * 64 + k * 4];
        a += q.x * we[4*k] + q.y * we[4*k+1] + q.z * we[4*k+2] + q.w * we[4*k+3];
      }
      acc[r] = a;
    }
  }

  // ---- combine halves + scatter-store (128B coalesced rows) ----
#pragma unroll
  for (int r = 0; r < 16; ++r) {
    if (r >= nv) break;
    const float v = acc[r] + __shfl_xor(acc[r], 32);
    const int sl = __shfl(slot, r);
    if (half == 0) e_sorted[(size_t)sl * 32 + g] = v + bedge;
  }
}

// ============================================================
// K5: one wave per node. e is PRECOMPUTED (e_sorted, CSR order, streaming).
// m = etrans(e) + pd + ps[src]; aggregate in registers.
// Edges processed in PAIRS: half-wave loads e-row of edge i, other half of
// edge i+1 (one coalesced 256-B load); next pair's e + ps prefetched into
// registers one iteration ahead. No atomics, no __syncthreads.
// ============================================================
__global__ __launch_bounds__(256) void agg_kernel(
    const float* __restrict__ x,
    const float* __restrict__ W_pre, const float* __restrict__ b_pre,
    const float* __restrict__ ps, const float* __restrict__ e_sorted,
    const int* __restrict__ srcs_s, const int* __restrict__ cnt,
    const int* __restrict__ base, float* __restrict__ aggs)
{
  __shared__ float sE[4][2][64];  // [wave][buf][pair of e-rows]
  __shared__ float sX[4][128];    // x row, per wave
  const int tid  = threadIdx.x;
  const int lane = tid & 63;
  const int w    = tid >> 6;
  const int g    = lane & 31;
  const int half = lane >> 5;
  const int t0   = half;          // tower of j0 = lane; j1 = lane+64 -> tower t0+2
  const int n    = blockIdx.x * 4 + w;

  // ---- W_pre e-part weights in registers ----
  float wp0[32], wp1[32];         // rows 64..95, columns for j0 / j1
#pragma unroll
  for (int f = 0; f < 32; ++f) {
    wp0[f] = W_pre[(size_t)(t0 * 96 + 64 + f) * 32 + g];
    wp1[f] = W_pre[(size_t)((t0 + 2) * 96 + 64 + f) * 32 + g];
  }

  // ---- stage x row, compute pd (dst-part, once per node) ----
  sX[w][lane]      = x[(size_t)n * 128 + lane];
  sX[w][lane + 64] = x[(size_t)n * 128 + 64 + lane];
  float pd0 = b_pre[t0 * 32 + g];
  float pd1 = b_pre[(t0 + 2) * 32 + g];
#pragma unroll
  for (int f = 0; f < 32; ++f) {
    pd0 += sX[w][t0 * 32 + f]       * W_pre[(size_t)(t0 * 96 + f) * 32 + g];
    pd1 += sX[w][(t0 + 2) * 32 + f] * W_pre[(size_t)((t0 + 2) * 96 + f) * 32 + g];
  }

  // ---- edge loop (pairs, depth-1 prefetch) ----
  const int c  = cnt[n];
  const int b0 = base[n];
  float sum0 = 0.f, sum1 = 0.f, sq0 = 0.f, sq1 = 0.f;
  float mx0 = -INFINITY, mx1 = -INFINITY, mn0 = INFINITY, mn1 = INFINITY;

  float ev = 0.f, pA0 = 0.f, pA1 = 0.f, pB0 = 0.f, pB1 = 0.f;
  if (c > 0) {
    const int cm = c - 1;
    ev = e_sorted[(size_t)(b0 + min(half, cm)) * 32 + g];
    const int sA = srcs_s[b0];
    const int sB = srcs_s[b0 + min(1, cm)];
    pA0 = ps[(size_t)sA * 128 + lane];
    pA1 = ps[(size_t)sA * 128 + 64 + lane];
    pB0 = ps[(size_t)sB * 128 + lane];
    pB1 = ps[(size_t)sB * 128 + 64 + lane];
  }

  for (int i = 0; i < c; i += 2) {
    const int buf = (i >> 1) & 1;
    const int cm  = c - 1;
    // prefetch pair i+2 (clamped; harmless cached re-reads at the tail)
    const float ev_n = e_sorted[(size_t)(b0 + min(i + 2 + half, cm)) * 32 + g];
    const int sAn = srcs_s[b0 + min(i + 2, cm)];
    const int sBn = srcs_s[b0 + min(i + 3, cm)];
    const float pA0n = ps[(size_t)sAn * 128 + lane];
    const float pA1n = ps[(size_t)sAn * 128 + 64 + lane];
    const float pB0n = ps[(size_t)sBn * 128 + lane];
    const float pB1n = ps[(size_t)sBn * 128 + 64 + lane];

    // stage current pair's e rows (lanes 0-31: edge i, lanes 32-63: edge i+1)
    sE[w][buf][lane] = ev;

    // edge i
    {
      float a0 = 0.f, a1 = 0.f;
      const float4* ep = (const float4*)&sE[w][buf][0];
#pragma unroll
      for (int k = 0; k < 8; ++k) {
        const float4 q = ep[k];
        a0 += q.x * wp0[4*k] + q.y * wp0[4*k+1] + q.z * wp0[4*k+2] + q.w * wp0[4*k+3];
        a1 += q.x * wp1[4*k] + q.y * wp1[4*k+1] + q.z * wp1[4*k+2] + q.w * wp1[4*k+3];
      }
      const float m0 = a0 + pd0 + pA0;
      const float m1 = a1 + pd1 + pA1;
      sum0 += m0; sq0 += m0 * m0; mx0 = fmaxf(mx0, m0); mn0 = fminf(mn0, m0);
      sum1 += m1; sq1 += m1 * m1; mx1 = fmaxf(mx1, m1); mn1 = fminf(mn1, m1);
    }
    // edge i+1 (wave-uniform branch)
    if (i + 1 < c) {
      float a0 = 0.f, a1 = 0.f;
      const float4* ep = (const float4*)&sE[w][buf][32];
#pragma unroll
      for (int k = 0; k < 8; ++k) {
        const float4 q = ep[k];
        a0 += q.x * wp0[4*k] + q.y * wp0[4*k+1] + q.z * wp0[4*k+2] + q.w * wp0[4*k+3];
        a1 += q.x * wp1[4*k] + q.y * wp1[4*k+1] + q.z * wp1[4*k+2] + q.w * wp1[4*k+3];
      }
      const float m0 = a0 + pd0 + pB0;
      const float m1 = a1 + pd1 + pB1;
      sum0 += m0; sq0 += m0 * m0; mx0 = fmaxf(mx0, m0); mn0 = fminf(mn0, m0);
      sum1 += m1; sq1 += m1 * m1; mx1 = fmaxf(mx1, m1); mn1 = fminf(mn1, m1);
    }
    // rotate prefetch registers
    ev = ev_n; pA0 = pA0n; pA1 = pA1n; pB0 = pB0n; pB1 = pB1n;
  }

  // ---- finalize ----
  const float csafe = fmaxf((float)c, 1.f);
  const float mean0 = sum0 / csafe, mean1 = sum1 / csafe;
  const float sd0 = sqrtf(fmaxf(sq0 / csafe - mean0 * mean0, 0.f) + 1e-5f);
  const float sd1 = sqrtf(fmaxf(sq1 / csafe - mean1 * mean1, 0.f) + 1e-5f);
  if (c == 0) { mx0 = mx1 = mn0 = mn1 = 0.f; }
  float* ag = aggs + (size_t)n * 512;
  ag[lane]       = mean0; ag[64 + lane]  = mean1;
  ag[128 + lane] = mx0;   ag[192 + lane] = mx1;
  ag[256 + lane] = mn0;   ag[320 + lane] = mn1;
  ag[384 + lane] = sd0;   ag[448 + lane] = sd1;
}

// ============================================================
// K6: scalers + W_post + W_lin + residual (8 nodes/block, 4-acc W reuse,
// float4 dot loops; W_post consumed via transposed WpT)
// ============================================================
__global__ __launch_bounds__(256) void post_kernel(
    const float* __restrict__ x, const float* __restrict__ aggs,
    const int* __restrict__ cnt,
    const float* __restrict__ WpT, const float* __restrict__ b_post,
    const float* __restrict__ W_lin, const float* __restrict__ b_lin,
    float* __restrict__ out, float avg_log)
{
  __shared__ float vec[8][4][416];
  __shared__ float h2[8][128];
  const int tid = threadIdx.x;
  const int j = tid & 127;
  const int t = j >> 5, g = j & 31;
  const int n0 = blockIdx.x * 8;

  // phase 1: build 416-feature per-tower vectors for 8 nodes
  for (int itn = 0; itn < 4; ++itn) {
    const int nl = itn * 2 + (tid >> 7);
    const int n = n0 + nl;
    const size_t o = (size_t)n * 128 + j;
    const float* ag = aggs + (size_t)n * 512;
    const float c = (float)cnt[n];
    const float mean = ag[j];
    const float mx   = ag[128 + j];
    const float mn   = ag[256 + j];
    const float sd   = ag[384 + j];
    const float logd = logf(c + 1.f);
    const float amp_s = logd / avg_log;
    const float att_s = (c == 0.f) ? 1.f : (avg_log / logd);
    float* v = vec[nl][t];
    v[g]        = x[o];
    v[32 + g]   = mean;          v[64 + g]   = mx;
    v[96 + g]   = mn;            v[128 + g]  = sd;
    v[160 + g]  = mean * amp_s;  v[192 + g]  = mx * amp_s;
    v[224 + g]  = mn * amp_s;    v[256 + g]  = sd * amp_s;
    v[288 + g]  = mean * att_s;  v[320 + g]  = mx * att_s;
    v[352 + g]  = mn * att_s;    v[384 + g]  = sd * att_s;
  }
  __syncthreads();

  // phase 2: h2 = vec @ W_post + b_post (4 node-accs per thread, float4)
  {
    const int nlb = tid >> 7;
    const float b = b_post[t * 32 + g];
    float acc0 = b, acc1 = b, acc2 = b, acc3 = b;
    const float4* Wp4 = (const float4*)(WpT + ((size_t)t * 32 + g) * 416);
    const float4* v0 = (const float4*)vec[nlb + 0][t];
    const float4* v1 = (const float4*)vec[nlb + 2][t];
    const float4* v2 = (const float4*)vec[nlb + 4][t];
    const float4* v3 = (const float4*)vec[nlb + 6][t];
    for (int f = 0; f < 104; ++f) {
      const float4 wv = Wp4[f];
      const float4 a = v0[f], bb = v1[f], cc = v2[f], dd = v3[f];
      acc0 += a.x  * wv.x + a.y  * wv.y + a.z  * wv.z + a.w  * wv.w;
      acc1 += bb.x * wv.x + bb.y * wv.y + bb.z * wv.z + bb.w * wv.w;
      acc2 += cc.x * wv.x + cc.y * wv.y + cc.z * wv.z + cc.w * wv.w;
      acc3 += dd.x * wv.x + dd.y * wv.y + dd.z * wv.z + dd.w * wv.w;
    }
    h2[nlb + 0][j] = acc0; h2[nlb + 2][j] = acc1;
    h2[nlb + 4][j] = acc2; h2[nlb + 6][j] = acc3;
  }
  __syncthreads();

  // phase 3: out = h2 @ W_lin.T + b_lin + x (float4; W_lin rows are k-contiguous)
  {
    const int nlb = tid >> 7;
    const float4* Wl4 = (const float4*)(W_lin + (size_t)j * 128);
    const float bl = b_lin[j];
    float a0 = bl, a1 = bl, a2 = bl, a3 = bl;
    const float4* h04 = (const float4*)h2[nlb + 0];
    const float4* h14 = (const float4*)h2[nlb + 2];
    const float4* h24 = (const float4*)h2[nlb + 4];
    const float4* h34 = (const float4*)h2[nlb + 6];
    for (int k = 0; k < 32; ++k) {
      const float4 wv = Wl4[k];
      const float4 a = h04[k], bb = h14[k], cc = h24[k], dd = h34[k];
      a0 += a.x  * wv.x + a.y  * wv.y + a.z  * wv.z + a.w  * wv.w;
      a1 += bb.x * wv.x + bb.y * wv.y + bb.z * wv.z + bb.w * wv.w;
      a2 += cc.x * wv.x + cc.y * wv.y + cc.z * wv.z + cc.w * wv.w;
      a3 += dd.x * wv.x + dd.y * wv.y + dd.z * wv.z + dd.w * wv.w;
    }
    const size_t b0 = (size_t)(n0 + nlb + 0) * 128 + j;
    const size_t b1 = (size_t)(n0 + nlb + 2) * 128 + j;
    const size_t b2 = (size_t)(n0 + nlb + 4) * 128 + j;
    const size_t b3 = (size_t)(n0 + nlb + 6) * 128 + j;
    out[b0] = a0 + x[b0];
    out[b1] = a1 + x[b1];
    out[b2] = a2 + x[b2];
    out[b3] = a3 + x[b3];
  }
}

extern "C" void kernel_launch(void* const* d_in, const int* in_sizes, int n_in,
                              void* d_out, int out_size, void* d_ws, size_t ws_size,
                              hipStream_t stream) {
  const float* x         = (const float*)d_in[0];
  const float* edge_attr = (const float*)d_in[1];
  const int*   ei        = (const int*)  d_in[2];
  const float* W_edge    = (const float*)d_in[3];
  const float* b_edge    = (const float*)d_in[4];
  const float* W_pre     = (const float*)d_in[5];
  const float* b_pre     = (const float*)d_in[6];
  const float* W_post    = (const float*)d_in[7];
  const float* b_post    = (const float*)d_in[8];
  const float* W_lin     = (const float*)d_in[9];
  const float* b_lin     = (const float*)d_in[10];
  float* out = (float*)d_out;

  const int N = in_sizes[0] / 128;
  const int E = in_sizes[2] / 2;

  // workspace: ps (N*128 f), aggs (N*512 f), e_sorted (E*32 f),
  //            srcs_s (E), cnt/base/fill (N each), WpT (4*416*32 f)
  float* ps       = (float*)d_ws;
  float* aggs     = ps + (size_t)N * 128;
  float* e_sorted = aggs + (size_t)N * 512;
  int*   srcs_s   = (int*)(e_sorted + (size_t)E * 32);
  int*   cnt      = srcs_s + E;
  int*   base     = cnt + N;
  int*   fill     = base + N;
  float* WpT      = (float*)(fill + N);

  hipMemsetAsync(cnt, 0, (size_t)N * 4, stream);

  const double counts[6] = {108477.0, 299931.0, 180702.0, 10767.0, 3.0, 2.0};
  double num = 0.0, den = 0.0;
  for (int i = 0; i < 6; ++i) { num += counts[i] * log((double)(i + 2)); den += counts[i]; }
  const float avg_log = (float)(num / den);

  wpt_kernel<<<(4 * 416 * 32 + 255) / 256, 256, 0, stream>>>(W_post, WpT);
  pre_kernel<<<N / 2, 256, 0, stream>>>(x, W_pre, ps);
  count_kernel<<<(E + 255) / 256, 256, 0, stream>>>(ei, cnt, E);
  scan_kernel<<<1, 256, 0, stream>>>(cnt, base, fill);
  escatter_kernel<<<(E + 63) / 64, 256, 0, stream>>>(edge_attr, ei, W_edge, b_edge,
                                                     fill, srcs_s, e_sorted, E);
  agg_kernel<<<N / 4, 256, 0, stream>>>(x, W_pre, b_pre, ps, e_sorted,
                                        srcs_s, cnt, base, aggs);
  post_kernel<<<N / 8, 256, 0, stream>>>(x, aggs, cnt, WpT, b_post,
                                         W_lin, b_lin, out, avg_log);
}